// Round 16
// baseline (225.867 us; speedup 1.0000x reference)
//
#include <hip/hip_runtime.h>
#include <hip/hip_bf16.h>
#include <math.h>

#define B_ 64
#define I_ 2048
#define K_ 16
#define N_ 32
#define D_ 32
#define SCH_ 16     // i-chunks for mfma sweep (128 i each)

typedef __attribute__((ext_vector_type(8))) short short8_t;   // 8 bf16
typedef __attribute__((ext_vector_type(4))) float f32x4_t;

// ws offsets (floats)
#define OFF_INT   0u           // inT   [I][K][B]        2097152
#define OFF_CT    2097152u     // cT    [N][I][B]        4194304
#define OFF_BT    6291456u     // bT    [N][I][B]        4194304
#define OFF_SPART 10485760u    // spart [N][SCH][B][D]   1048576
#define OFF_OFRAG 11534336u    // ofrag [N][4][64] uint4 =  65536 slot
#define OFF_XFRAG 11599872u    // xfrag [4][1024][64] uint4 = 1048576 f-slots
#define OFF_WBF   12648448u    // wbf   bf16 [N][I][D][K] = 16777216 f-slots (64 MiB)
// total 29425664 floats ≈ 112.25 MiB (ws = 512 MiB per harness poison fills)

__device__ __forceinline__ unsigned int pk_bf16(float lo, float hi) {
    union { __hip_bfloat162 h2; unsigned int u; } cv;
    cv.h2 = __float22bfloat162_rn(float2{lo, hi});
    return cv.u;
}

// ---------------- W fp32 -> plain bf16 copy (pure streaming; r15-verified) ------
__global__ __launch_bounds__(256) void k_wconv(const float* __restrict__ W,
                                               uint4* __restrict__ wbf4) {
    const size_t tid = (size_t)blockIdx.x * 256 + threadIdx.x;  // one uint4 (8 bf16)
    const float4* W4 = (const float4*)W;
    const float4 a = W4[2 * tid];
    const float4 b = W4[2 * tid + 1];
    uint4 o;
    o.x = pk_bf16(a.x, a.y); o.y = pk_bf16(a.z, a.w);
    o.z = pk_bf16(b.x, b.y); o.w = pk_bf16(b.z, b.w);
    wbf4[tid] = o;
}

// ---------------- fused: transpose inputs -> inT + pack xfrag (r12-verified) ----
__global__ __launch_bounds__(256) void k_prep(const float* __restrict__ in,
                                              float* __restrict__ inT,
                                              uint4* __restrict__ xfrag) {
    __shared__ float lds[B_][K_ + 1];
    const int i = blockIdx.x;
    const int t = threadIdx.x;
    const int b = t >> 2, kq = t & 3;
    const float4 v = *(const float4*)(in + ((size_t)b * I_ + i) * K_ + kq * 4);
    lds[b][kq * 4 + 0] = v.x; lds[b][kq * 4 + 1] = v.y;
    lds[b][kq * 4 + 2] = v.z; lds[b][kq * 4 + 3] = v.w;
    __syncthreads();
#pragma unroll
    for (int q = 0; q < 4; ++q) {
        const int j = t + q * 256;          // j = k*64 + b
        const int k = j >> 6, bb = j & 63;
        inT[(size_t)i * (K_ * B_) + j] = lds[bb][k];
    }
    if (t < 128) {
        const int m = t >> 5, r = t & 31, gl = r >> 4, kl = r & 15;
        const int bb = m * 16 + kl, k0 = 8 * gl;
        union { unsigned int u[4]; uint4 q; } o;
#pragma unroll
        for (int p = 0; p < 4; ++p)
            o.u[p] = pk_bf16(lds[bb][k0 + 2 * p], lds[bb][k0 + 2 * p + 1]);
        xfrag[((size_t)m * 1024 + (i >> 1)) * 64 + (2 * (i & 1) + gl) * 16 + kl] = o.q;
    }
}

// ---------------- MFMA s-sweep (plain-wbf B-frags; r15-verified) ----------------
template<int UNIFORM>
__global__ __launch_bounds__(512, 2) void k_sweep_mfma(const uint4* __restrict__ wbf4,
                                                       const uint4* __restrict__ xfrag,
                                                       const float* __restrict__ cT,
                                                       float* __restrict__ spart) {
    __shared__ float red[2][B_][D_ + 1];
    const int n = blockIdx.y, ch = blockIdx.x;
    const int t = threadIdx.x, w = t >> 6, l = t & 63;
    const int m = w >> 1, ks = w & 1;
    const int g = l >> 4;

    f32x4_t acc0 = {0.f, 0.f, 0.f, 0.f};
    f32x4_t acc1 = {0.f, 0.f, 0.f, 0.f};

    const uint4* xf = xfrag + (size_t)m * 65536 + l;            // + kk*64
    // B-frag: i = 2kk+(g>>1), d=(l&15)+16nt, k0=8(g&1); granule = d*2+(g&1)
    const uint4* wb = wbf4 + (size_t)n * (I_ * 64)
                    + (size_t)(g >> 1) * 64 + (l & 15) * 2 + (g & 1);
    const int kk0 = ch * 64 + ks * 32;

    for (int tt = 0; tt < 32; ++tt) {
        const int kk = kk0 + tt;
        union { uint4 q; unsigned int u[4]; } xv;
        xv.q = xf[(size_t)kk * 64];
        union { unsigned int u[4]; short8_t v; } af;
        if (UNIFORM) {
            af.u[0] = xv.u[0]; af.u[1] = xv.u[1];
            af.u[2] = xv.u[2]; af.u[3] = xv.u[3];
        } else {
            const float c = cT[((size_t)n * I_ + 2 * kk + (l >> 5)) * B_
                               + m * 16 + (l & 15)];
#pragma unroll
            for (int p = 0; p < 4; ++p) {
                const unsigned int uu = xv.u[p];
                const float lo = __uint_as_float(uu << 16);
                const float hi = __uint_as_float(uu & 0xffff0000u);
                af.u[p] = pk_bf16(lo * c, hi * c);
            }
        }
        union { uint4 q; short8_t v; } b0, b1;
        b0.q = wb[(size_t)kk * 128];          // nt=0 (d 0..15)
        b1.q = wb[(size_t)kk * 128 + 32];     // nt=1 (d 16..31)

        acc0 = __builtin_amdgcn_mfma_f32_16x16x32_bf16(af.v, b0.v, acc0, 0, 0, 0);
        acc1 = __builtin_amdgcn_mfma_f32_16x16x32_bf16(af.v, b1.v, acc1, 0, 0, 0);
    }

#pragma unroll
    for (int r = 0; r < 4; ++r) {
        const int row = m * 16 + (l >> 4) * 4 + r;
        red[ks][row][(l & 15)]      = acc0[r];
        red[ks][row][16 + (l & 15)] = acc1[r];
    }
    __syncthreads();
#pragma unroll
    for (int q = 0; q < 4; ++q) {
        const int j = q * 512 + t;                  // j = b*32 + d
        const int b = j >> 5, d = j & 31;
        spart[((size_t)n * SCH_ + ch) * (B_ * D_) + j] = red[0][b][d] + red[1][b][d];
    }
}

// ---------------- reduce + squash; emit ofrag or final out (r12-verified) -------
template<int FINAL>
__global__ __launch_bounds__(256) void k_reduce(const float* __restrict__ spart,
                                                unsigned int* __restrict__ ofrag_u32,
                                                float* __restrict__ out,
                                                float prescale) {
    const int gt = blockIdx.x * 256 + threadIdx.x;   // N*B*D threads
    const int n = gt >> 11;
    const int rem = gt & 2047;                        // b*32 + d
    const int b = rem >> 5, d = rem & 31;
    const float* sp = spart + (size_t)n * (SCH_ * B_ * D_) + rem;
    float s = 0.f;
#pragma unroll
    for (int p = 0; p < SCH_; ++p) s += sp[p * (B_ * D_)];
    s *= prescale;

    float sq = s * s;
#pragma unroll
    for (int off = 16; off >= 1; off >>= 1) sq += __shfl_xor(sq, off, 64);
    const float scale = sq / ((1.0f + sq) * sqrtf(sq + 1e-7f));
    const float o = scale * s;
    if (FINAL) {
        out[((size_t)b * N_ + n) * D_ + d] = o;       // [B][N][D]
    } else {
        const float o_next = __shfl_down(o, 1, 64);
        if ((d & 1) == 0) {
            const unsigned int val = pk_bf16(o, o_next);
            const int l = (d >> 3) * 16 + (b & 15);
            ofrag_u32[(((n * 4 + (b >> 4)) * 64) + l) * 4 + ((d & 7) >> 1)] = val;
        }
    }
}

// ---------------- fused b-update + softmax (r12 structure, A-frag from wbf) -----
// af.u[p] = bf16(W[8g+2p][kl]) | bf16(W[8g+2p+1][kl])<<16, assembled from the
// plain bf16 row: u32 j2 = d*8 + (kl>>1), half picked by kl&1. Bit-identical
// to the old wfu path (same pk_bf16 rounding applied in wconv).
template<int FIRST>
__global__ __launch_bounds__(512, 2) void k_updsm(const unsigned int* __restrict__ wbfu,
                                                  const float* __restrict__ inT,
                                                  const uint4* __restrict__ ofrag,
                                                  float* __restrict__ bT,
                                                  float* __restrict__ cT) {
    const int t = threadIdx.x, w = t >> 6, l = t & 63;
    const int btile = w & 3;
    const int i = blockIdx.x * 2 + (w >> 2);
    const int g = l >> 4, kl = l & 15;
    const int bp = btile * 16 + kl;           // b'
    const int kh = kl >> 1;
    const bool odd = (kl & 1) != 0;

    float x4[4];
    {
        const float* xp = inT + (size_t)i * (K_ * B_) + bp;
#pragma unroll
        for (int r = 0; r < 4; ++r) x4[r] = xp[(4 * g + r) * B_];
    }

    const unsigned int* wr = wbfu + (size_t)i * 256 + 64 * g + kh;

    float bn[N_];
#pragma unroll
    for (int n = 0; n < N_; ++n) {
        union { uint4 q; short8_t v; } of, af;
        of.q = ofrag[(n * 4 + btile) * 64 + l];
        const unsigned int* wn = wr + (size_t)n * (I_ * 256);
        union { unsigned int u[4]; short8_t v; } au;
#pragma unroll
        for (int p = 0; p < 4; ++p) {
            const unsigned int A = wn[16 * p];        // d = 8g+2p
            const unsigned int Bv = wn[16 * p + 8];   // d = 8g+2p+1
            au.u[p] = odd ? ((A >> 16) | (Bv & 0xffff0000u))
                          : ((A & 0xffffu) | (Bv << 16));
        }
        af.q = *(uint4*)&au;
        f32x4_t acc = {0.f, 0.f, 0.f, 0.f};
        acc = __builtin_amdgcn_mfma_f32_16x16x32_bf16(af.v, of.v, acc, 0, 0, 0);
        float gp = 0.f;
#pragma unroll
        for (int r = 0; r < 4; ++r) gp = fmaf(acc[r], x4[r], gp);
        gp += __shfl_xor(gp, 16, 64);
        gp += __shfl_xor(gp, 32, 64);
        const size_t bi = ((size_t)n * I_ + i) * B_ + bp;
        if (FIRST) {
            if (l < 16) bT[bi] = gp;
        } else {
            gp += bT[bi];
        }
        bn[n] = gp;
    }

    float mx = bn[0];
#pragma unroll
    for (int n = 1; n < N_; ++n) mx = fmaxf(mx, bn[n]);
    float sum = 0.f;
#pragma unroll
    for (int n = 0; n < N_; ++n) { bn[n] = __expf(bn[n] - mx); sum += bn[n]; }
    const float inv = 1.0f / sum;
    if (l < 16) {
#pragma unroll
        for (int n = 0; n < N_; ++n)
            cT[((size_t)n * I_ + i) * B_ + bp] = bn[n] * inv;
    }
}

extern "C" void kernel_launch(void* const* d_in, const int* in_sizes, int n_in,
                              void* d_out, int out_size, void* d_ws, size_t ws_size,
                              hipStream_t stream) {
    const float* inputs = (const float*)d_in[0];
    const float* W      = (const float*)d_in[1];
    float* out = (float*)d_out;
    float* ws  = (float*)d_ws;
    float* inT   = ws + OFF_INT;
    float* cT    = ws + OFF_CT;
    float* bT    = ws + OFF_BT;
    float* spart = ws + OFF_SPART;
    unsigned int* ofrag_u32 = (unsigned int*)(ws + OFF_OFRAG);
    uint4* ofrag = (uint4*)(ws + OFF_OFRAG);
    uint4* xfrag = (uint4*)(ws + OFF_XFRAG);
    uint4* wbf4  = (uint4*)(ws + OFF_WBF);
    const unsigned int* wbfu = (const unsigned int*)(ws + OFF_WBF);

    k_wconv<<<(N_ * I_ * D_ * K_) / (8 * 256), 256, 0, stream>>>(W, wbf4);
    k_prep<<<I_, 256, 0, stream>>>(inputs, inT, xfrag);
    // r = 0 (uniform c = 1/N as prescale)
    k_sweep_mfma<1><<<dim3(SCH_, N_), 512, 0, stream>>>(wbf4, xfrag, cT, spart);
    k_reduce<0><<<256, 256, 0, stream>>>(spart, ofrag_u32, out, 1.0f / N_);
    k_updsm<1><<<I_ / 2, 512, 0, stream>>>(wbfu, inT, ofrag, bT, cT);
    // r = 1
    k_sweep_mfma<0><<<dim3(SCH_, N_), 512, 0, stream>>>(wbf4, xfrag, cT, spart);
    k_reduce<0><<<256, 256, 0, stream>>>(spart, ofrag_u32, out, 1.0f);
    k_updsm<0><<<I_ / 2, 512, 0, stream>>>(wbfu, inT, ofrag, bT, cT);
    // r = 2
    k_sweep_mfma<0><<<dim3(SCH_, N_), 512, 0, stream>>>(wbf4, xfrag, cT, spart);
    k_reduce<1><<<256, 256, 0, stream>>>(spart, ofrag_u32, out, 1.0f);
}

// Round 17
// 194.846 us; speedup vs baseline: 1.1592x; 1.1592x over previous
//
#include <hip/hip_runtime.h>
#include <hip/hip_bf16.h>
#include <math.h>

#define B_ 64
#define I_ 2048
#define K_ 16
#define N_ 32
#define D_ 32
#define SCH_ 16     // i-chunks for mfma sweep (128 i each)

typedef __attribute__((ext_vector_type(8))) short short8_t;   // 8 bf16
typedef __attribute__((ext_vector_type(4))) float f32x4_t;

// ws offsets (floats)
#define OFF_INT   0u           // inT   [I][K][B]        2097152
#define OFF_CT    2097152u     // cT    [N][I][B]        4194304
#define OFF_BT    6291456u     // bT    [N][I][B]        4194304
#define OFF_SPART 10485760u    // spart [N][SCH][B][D]   1048576
#define OFF_OFRAG 11534336u    // ofrag [N][4][64] uint4 = 32768 f-slots (+pad)
#define OFF_XFRAG 11599872u    // xfrag [4][1024][64] uint4 = 1048576 f-slots
#define OFF_WBF   12648448u    // wbf   bf16 [N][I][D][K]  = 16777216 f-slots (64 MiB)
#define OFF_WFU   29425664u    // wfu   [N][I][64] uint4   = 16777216 f-slots (64 MiB)
// total 46202880 floats = 176.25 MiB (ws = 512 MiB per harness poison fills)

__device__ __forceinline__ unsigned int pk_bf16(float lo, float hi) {
    union { __hip_bfloat162 h2; unsigned int u; } cv;
    cv.h2 = __float22bfloat162_rn(float2{lo, hi});
    return cv.u;
}

// ---------------- W fp32 -> plain bf16 copy (pure streaming; r15-verified) ------
__global__ __launch_bounds__(256) void k_wconv(const float* __restrict__ W,
                                               uint4* __restrict__ wbf4) {
    const size_t tid = (size_t)blockIdx.x * 256 + threadIdx.x;  // one uint4 (8 bf16)
    const float4* W4 = (const float4*)W;
    const float4 a = W4[2 * tid];
    const float4 b = W4[2 * tid + 1];
    uint4 o;
    o.x = pk_bf16(a.x, a.y); o.y = pk_bf16(a.z, a.w);
    o.z = pk_bf16(b.x, b.y); o.w = pk_bf16(b.z, b.w);
    wbf4[tid] = o;
}

// ---------------- wbf -> wfu (update A-frags), pure u32 shuffle stream ----------
// r16-verified formula, moved to a dedicated TLP-rich pass: bit-identical to the
// old wfu path. Reads L3-resident wbf, writes coalesced wfu.
__global__ __launch_bounds__(256) void k_wfupack(const unsigned int* __restrict__ wbfu,
                                                 uint4* __restrict__ wfu) {
    const size_t tid = (size_t)blockIdx.x * 256 + threadIdx.x;  // (n*I+i)*64 + l
    const int l = tid & 63;
    const size_t row = tid >> 6;                 // n*I + i
    const int g = l >> 4, kl = l & 15, kh = kl >> 1;
    const bool odd = (kl & 1) != 0;
    const unsigned int* wr = wbfu + row * 256 + 64 * g + kh;
    union { unsigned int u[4]; uint4 q; } o;
#pragma unroll
    for (int p = 0; p < 4; ++p) {
        const unsigned int A  = wr[16 * p];       // d = 8g+2p
        const unsigned int Bv = wr[16 * p + 8];   // d = 8g+2p+1
        o.u[p] = odd ? ((A >> 16) | (Bv & 0xffff0000u))
                     : ((A & 0xffffu) | (Bv << 16));
    }
    wfu[tid] = o.q;
}

// ---------------- fused: transpose inputs -> inT + pack xfrag (r12-verified) ----
__global__ __launch_bounds__(256) void k_prep(const float* __restrict__ in,
                                              float* __restrict__ inT,
                                              uint4* __restrict__ xfrag) {
    __shared__ float lds[B_][K_ + 1];
    const int i = blockIdx.x;
    const int t = threadIdx.x;
    const int b = t >> 2, kq = t & 3;
    const float4 v = *(const float4*)(in + ((size_t)b * I_ + i) * K_ + kq * 4);
    lds[b][kq * 4 + 0] = v.x; lds[b][kq * 4 + 1] = v.y;
    lds[b][kq * 4 + 2] = v.z; lds[b][kq * 4 + 3] = v.w;
    __syncthreads();
#pragma unroll
    for (int q = 0; q < 4; ++q) {
        const int j = t + q * 256;          // j = k*64 + b
        const int k = j >> 6, bb = j & 63;
        inT[(size_t)i * (K_ * B_) + j] = lds[bb][k];
    }
    if (t < 128) {
        const int m = t >> 5, r = t & 31, gl = r >> 4, kl = r & 15;
        const int bb = m * 16 + kl, k0 = 8 * gl;
        union { unsigned int u[4]; uint4 q; } o;
#pragma unroll
        for (int p = 0; p < 4; ++p)
            o.u[p] = pk_bf16(lds[bb][k0 + 2 * p], lds[bb][k0 + 2 * p + 1]);
        xfrag[((size_t)m * 1024 + (i >> 1)) * 64 + (2 * (i & 1) + gl) * 16 + kl] = o.q;
    }
}

// ---------------- MFMA s-sweep (plain-wbf B-frags; r15-verified) ----------------
template<int UNIFORM>
__global__ __launch_bounds__(512, 2) void k_sweep_mfma(const uint4* __restrict__ wbf4,
                                                       const uint4* __restrict__ xfrag,
                                                       const float* __restrict__ cT,
                                                       float* __restrict__ spart) {
    __shared__ float red[2][B_][D_ + 1];
    const int n = blockIdx.y, ch = blockIdx.x;
    const int t = threadIdx.x, w = t >> 6, l = t & 63;
    const int m = w >> 1, ks = w & 1;
    const int g = l >> 4;

    f32x4_t acc0 = {0.f, 0.f, 0.f, 0.f};
    f32x4_t acc1 = {0.f, 0.f, 0.f, 0.f};

    const uint4* xf = xfrag + (size_t)m * 65536 + l;            // + kk*64
    const uint4* wb = wbf4 + (size_t)n * (I_ * 64)
                    + (size_t)(g >> 1) * 64 + (l & 15) * 2 + (g & 1);
    const int kk0 = ch * 64 + ks * 32;

    for (int tt = 0; tt < 32; ++tt) {
        const int kk = kk0 + tt;
        union { uint4 q; unsigned int u[4]; } xv;
        xv.q = xf[(size_t)kk * 64];
        union { unsigned int u[4]; short8_t v; } af;
        if (UNIFORM) {
            af.u[0] = xv.u[0]; af.u[1] = xv.u[1];
            af.u[2] = xv.u[2]; af.u[3] = xv.u[3];
        } else {
            const float c = cT[((size_t)n * I_ + 2 * kk + (l >> 5)) * B_
                               + m * 16 + (l & 15)];
#pragma unroll
            for (int p = 0; p < 4; ++p) {
                const unsigned int uu = xv.u[p];
                const float lo = __uint_as_float(uu << 16);
                const float hi = __uint_as_float(uu & 0xffff0000u);
                af.u[p] = pk_bf16(lo * c, hi * c);
            }
        }
        union { uint4 q; short8_t v; } b0, b1;
        b0.q = wb[(size_t)kk * 128];          // nt=0 (d 0..15)
        b1.q = wb[(size_t)kk * 128 + 32];     // nt=1 (d 16..31)

        acc0 = __builtin_amdgcn_mfma_f32_16x16x32_bf16(af.v, b0.v, acc0, 0, 0, 0);
        acc1 = __builtin_amdgcn_mfma_f32_16x16x32_bf16(af.v, b1.v, acc1, 0, 0, 0);
    }

#pragma unroll
    for (int r = 0; r < 4; ++r) {
        const int row = m * 16 + (l >> 4) * 4 + r;
        red[ks][row][(l & 15)]      = acc0[r];
        red[ks][row][16 + (l & 15)] = acc1[r];
    }
    __syncthreads();
#pragma unroll
    for (int q = 0; q < 4; ++q) {
        const int j = q * 512 + t;                  // j = b*32 + d
        const int b = j >> 5, d = j & 31;
        spart[((size_t)n * SCH_ + ch) * (B_ * D_) + j] = red[0][b][d] + red[1][b][d];
    }
}

// ---------------- reduce + squash; emit ofrag or final out (r12-verified) -------
template<int FINAL>
__global__ __launch_bounds__(256) void k_reduce(const float* __restrict__ spart,
                                                unsigned int* __restrict__ ofrag_u32,
                                                float* __restrict__ out,
                                                float prescale) {
    const int gt = blockIdx.x * 256 + threadIdx.x;   // N*B*D threads
    const int n = gt >> 11;
    const int rem = gt & 2047;                        // b*32 + d
    const int b = rem >> 5, d = rem & 31;
    const float* sp = spart + (size_t)n * (SCH_ * B_ * D_) + rem;
    float s = 0.f;
#pragma unroll
    for (int p = 0; p < SCH_; ++p) s += sp[p * (B_ * D_)];
    s *= prescale;

    float sq = s * s;
#pragma unroll
    for (int off = 16; off >= 1; off >>= 1) sq += __shfl_xor(sq, off, 64);
    const float scale = sq / ((1.0f + sq) * sqrtf(sq + 1e-7f));
    const float o = scale * s;
    if (FINAL) {
        out[((size_t)b * N_ + n) * D_ + d] = o;       // [B][N][D]
    } else {
        const float o_next = __shfl_down(o, 1, 64);
        if ((d & 1) == 0) {
            const unsigned int val = pk_bf16(o, o_next);
            const int l = (d >> 3) * 16 + (b & 15);
            ofrag_u32[(((n * 4 + (b >> 4)) * 64) + l) * 4 + ((d & 7) >> 1)] = val;
        }
    }
}

// ---------------- fused b-update + softmax (r12-verified, reads wfu) ------------
template<int FIRST>
__global__ __launch_bounds__(512, 2) void k_updsm(const uint4* __restrict__ wfu,
                                                  const float* __restrict__ inT,
                                                  const uint4* __restrict__ ofrag,
                                                  float* __restrict__ bT,
                                                  float* __restrict__ cT) {
    const int t = threadIdx.x, w = t >> 6, l = t & 63;
    const int btile = w & 3;
    const int i = blockIdx.x * 2 + (w >> 2);
    const int g = l >> 4, kl = l & 15;
    const int bp = btile * 16 + kl;           // b'

    float x4[4];
    {
        const float* xp = inT + (size_t)i * (K_ * B_) + bp;
#pragma unroll
        for (int r = 0; r < 4; ++r) x4[r] = xp[(4 * g + r) * B_];
    }

    float bn[N_];
#pragma unroll
    for (int n = 0; n < N_; ++n) {
        union { uint4 q; short8_t v; } of, af;
        of.q = ofrag[(n * 4 + btile) * 64 + l];
        af.q = wfu[((size_t)n * I_ + i) * 64 + l];
        f32x4_t acc = {0.f, 0.f, 0.f, 0.f};
        acc = __builtin_amdgcn_mfma_f32_16x16x32_bf16(af.v, of.v, acc, 0, 0, 0);
        float gp = 0.f;
#pragma unroll
        for (int r = 0; r < 4; ++r) gp = fmaf(acc[r], x4[r], gp);
        gp += __shfl_xor(gp, 16, 64);
        gp += __shfl_xor(gp, 32, 64);
        const size_t bi = ((size_t)n * I_ + i) * B_ + bp;
        if (FIRST) {
            if (l < 16) bT[bi] = gp;
        } else {
            gp += bT[bi];
        }
        bn[n] = gp;
    }

    float mx = bn[0];
#pragma unroll
    for (int n = 1; n < N_; ++n) mx = fmaxf(mx, bn[n]);
    float sum = 0.f;
#pragma unroll
    for (int n = 0; n < N_; ++n) { bn[n] = __expf(bn[n] - mx); sum += bn[n]; }
    const float inv = 1.0f / sum;
    if (l < 16) {
#pragma unroll
        for (int n = 0; n < N_; ++n)
            cT[((size_t)n * I_ + i) * B_ + bp] = bn[n] * inv;
    }
}

extern "C" void kernel_launch(void* const* d_in, const int* in_sizes, int n_in,
                              void* d_out, int out_size, void* d_ws, size_t ws_size,
                              hipStream_t stream) {
    const float* inputs = (const float*)d_in[0];
    const float* W      = (const float*)d_in[1];
    float* out = (float*)d_out;
    float* ws  = (float*)d_ws;
    float* inT   = ws + OFF_INT;
    float* cT    = ws + OFF_CT;
    float* bT    = ws + OFF_BT;
    float* spart = ws + OFF_SPART;
    unsigned int* ofrag_u32 = (unsigned int*)(ws + OFF_OFRAG);
    uint4* ofrag = (uint4*)(ws + OFF_OFRAG);
    uint4* xfrag = (uint4*)(ws + OFF_XFRAG);
    uint4* wbf4  = (uint4*)(ws + OFF_WBF);
    const unsigned int* wbfu = (const unsigned int*)(ws + OFF_WBF);
    uint4* wfu   = (uint4*)(ws + OFF_WFU);

    k_wconv<<<(N_ * I_ * D_ * K_) / (8 * 256), 256, 0, stream>>>(W, wbf4);
    k_prep<<<I_, 256, 0, stream>>>(inputs, inT, xfrag);
    k_wfupack<<<(N_ * I_ * 64) / 256, 256, 0, stream>>>(wbfu, wfu);
    // r = 0 (uniform c = 1/N as prescale)
    k_sweep_mfma<1><<<dim3(SCH_, N_), 512, 0, stream>>>(wbf4, xfrag, cT, spart);
    k_reduce<0><<<256, 256, 0, stream>>>(spart, ofrag_u32, out, 1.0f / N_);
    k_updsm<1><<<I_ / 2, 512, 0, stream>>>(wfu, inT, ofrag, bT, cT);
    // r = 1
    k_sweep_mfma<0><<<dim3(SCH_, N_), 512, 0, stream>>>(wbf4, xfrag, cT, spart);
    k_reduce<0><<<256, 256, 0, stream>>>(spart, ofrag_u32, out, 1.0f);
    k_updsm<0><<<I_ / 2, 512, 0, stream>>>(wfu, inT, ofrag, bT, cT);
    // r = 2
    k_sweep_mfma<0><<<dim3(SCH_, N_), 512, 0, stream>>>(wbf4, xfrag, cT, spart);
    k_reduce<1><<<256, 256, 0, stream>>>(spart, ofrag_u32, out, 1.0f);
}

// Round 18
// 187.410 us; speedup vs baseline: 1.2052x; 1.0397x over previous
//
#include <hip/hip_runtime.h>
#include <hip/hip_bf16.h>
#include <math.h>

#define B_ 64
#define I_ 2048
#define K_ 16
#define N_ 32
#define D_ 32
#define SCH_ 16     // i-chunks for mfma sweep (128 i each)

#define AS1 __attribute__((address_space(1)))
#define AS3 __attribute__((address_space(3)))

typedef __attribute__((ext_vector_type(8))) short short8_t;   // 8 bf16
typedef __attribute__((ext_vector_type(4))) float f32x4_t;

// ws offsets (floats)
#define OFF_INT   0u           // inT   [I][K][B]        2097152
#define OFF_CT    2097152u     // cT    [N][I][B]        4194304
#define OFF_BT    6291456u     // bT    [N][I][B]        4194304
#define OFF_SPART 10485760u    // spart [N][SCH][B][D]   1048576
#define OFF_OFRAG 11534336u    // ofrag [N][4][64] uint4 = 32768 f-slots (+pad)
#define OFF_XFRAG 11599872u    // xfrag [4][1024][64] uint4 = 1048576 f-slots
#define OFF_WBF   12648448u    // wbf   bf16 [N][I][D][K]  = 16777216 f-slots (64 MiB)
// total 29425664 floats ≈ 112.25 MiB (ws = 512 MiB per harness poison fills)

__device__ __forceinline__ unsigned int pk_bf16(float lo, float hi) {
    union { __hip_bfloat162 h2; unsigned int u; } cv;
    cv.h2 = __float22bfloat162_rn(float2{lo, hi});
    return cv.u;
}

// ---------------- W fp32 -> plain bf16 copy (pure streaming; r15-verified) ------
__global__ __launch_bounds__(256) void k_wconv(const float* __restrict__ W,
                                               uint4* __restrict__ wbf4) {
    const size_t tid = (size_t)blockIdx.x * 256 + threadIdx.x;  // one uint4 (8 bf16)
    const float4* W4 = (const float4*)W;
    const float4 a = W4[2 * tid];
    const float4 b = W4[2 * tid + 1];
    uint4 o;
    o.x = pk_bf16(a.x, a.y); o.y = pk_bf16(a.z, a.w);
    o.z = pk_bf16(b.x, b.y); o.w = pk_bf16(b.z, b.w);
    wbf4[tid] = o;
}

// ---------------- fused: transpose inputs -> inT + pack xfrag (r12-verified) ----
__global__ __launch_bounds__(256) void k_prep(const float* __restrict__ in,
                                              float* __restrict__ inT,
                                              uint4* __restrict__ xfrag) {
    __shared__ float lds[B_][K_ + 1];
    const int i = blockIdx.x;
    const int t = threadIdx.x;
    const int b = t >> 2, kq = t & 3;
    const float4 v = *(const float4*)(in + ((size_t)b * I_ + i) * K_ + kq * 4);
    lds[b][kq * 4 + 0] = v.x; lds[b][kq * 4 + 1] = v.y;
    lds[b][kq * 4 + 2] = v.z; lds[b][kq * 4 + 3] = v.w;
    __syncthreads();
#pragma unroll
    for (int q = 0; q < 4; ++q) {
        const int j = t + q * 256;          // j = k*64 + b
        const int k = j >> 6, bb = j & 63;
        inT[(size_t)i * (K_ * B_) + j] = lds[bb][k];
    }
    if (t < 128) {
        const int m = t >> 5, r = t & 31, gl = r >> 4, kl = r & 15;
        const int bb = m * 16 + kl, k0 = 8 * gl;
        union { unsigned int u[4]; uint4 q; } o;
#pragma unroll
        for (int p = 0; p < 4; ++p)
            o.u[p] = pk_bf16(lds[bb][k0 + 2 * p], lds[bb][k0 + 2 * p + 1]);
        xfrag[((size_t)m * 1024 + (i >> 1)) * 64 + (2 * (i & 1) + gl) * 16 + kl] = o.q;
    }
}

// ---------------- MFMA s-sweep (plain-wbf B-frags; r15-verified) ----------------
template<int UNIFORM>
__global__ __launch_bounds__(512, 2) void k_sweep_mfma(const uint4* __restrict__ wbf4,
                                                       const uint4* __restrict__ xfrag,
                                                       const float* __restrict__ cT,
                                                       float* __restrict__ spart) {
    __shared__ float red[2][B_][D_ + 1];
    const int n = blockIdx.y, ch = blockIdx.x;
    const int t = threadIdx.x, w = t >> 6, l = t & 63;
    const int m = w >> 1, ks = w & 1;
    const int g = l >> 4;

    f32x4_t acc0 = {0.f, 0.f, 0.f, 0.f};
    f32x4_t acc1 = {0.f, 0.f, 0.f, 0.f};

    const uint4* xf = xfrag + (size_t)m * 65536 + l;            // + kk*64
    const uint4* wb = wbf4 + (size_t)n * (I_ * 64)
                    + (size_t)(g >> 1) * 64 + (l & 15) * 2 + (g & 1);
    const int kk0 = ch * 64 + ks * 32;

    for (int tt = 0; tt < 32; ++tt) {
        const int kk = kk0 + tt;
        union { uint4 q; unsigned int u[4]; } xv;
        xv.q = xf[(size_t)kk * 64];
        union { unsigned int u[4]; short8_t v; } af;
        if (UNIFORM) {
            af.u[0] = xv.u[0]; af.u[1] = xv.u[1];
            af.u[2] = xv.u[2]; af.u[3] = xv.u[3];
        } else {
            const float c = cT[((size_t)n * I_ + 2 * kk + (l >> 5)) * B_
                               + m * 16 + (l & 15)];
#pragma unroll
            for (int p = 0; p < 4; ++p) {
                const unsigned int uu = xv.u[p];
                const float lo = __uint_as_float(uu << 16);
                const float hi = __uint_as_float(uu & 0xffff0000u);
                af.u[p] = pk_bf16(lo * c, hi * c);
            }
        }
        union { uint4 q; short8_t v; } b0, b1;
        b0.q = wb[(size_t)kk * 128];          // nt=0 (d 0..15)
        b1.q = wb[(size_t)kk * 128 + 32];     // nt=1 (d 16..31)

        acc0 = __builtin_amdgcn_mfma_f32_16x16x32_bf16(af.v, b0.v, acc0, 0, 0, 0);
        acc1 = __builtin_amdgcn_mfma_f32_16x16x32_bf16(af.v, b1.v, acc1, 0, 0, 0);
    }

#pragma unroll
    for (int r = 0; r < 4; ++r) {
        const int row = m * 16 + (l >> 4) * 4 + r;
        red[ks][row][(l & 15)]      = acc0[r];
        red[ks][row][16 + (l & 15)] = acc1[r];
    }
    __syncthreads();
#pragma unroll
    for (int q = 0; q < 4; ++q) {
        const int j = q * 512 + t;                  // j = b*32 + d
        const int b = j >> 5, d = j & 31;
        spart[((size_t)n * SCH_ + ch) * (B_ * D_) + j] = red[0][b][d] + red[1][b][d];
    }
}

// ---------------- reduce + squash; emit ofrag or final out (r12-verified) -------
template<int FINAL>
__global__ __launch_bounds__(256) void k_reduce(const float* __restrict__ spart,
                                                unsigned int* __restrict__ ofrag_u32,
                                                float* __restrict__ out,
                                                float prescale) {
    const int gt = blockIdx.x * 256 + threadIdx.x;   // N*B*D threads
    const int n = gt >> 11;
    const int rem = gt & 2047;                        // b*32 + d
    const int b = rem >> 5, d = rem & 31;
    const float* sp = spart + (size_t)n * (SCH_ * B_ * D_) + rem;
    float s = 0.f;
#pragma unroll
    for (int p = 0; p < SCH_; ++p) s += sp[p * (B_ * D_)];
    s *= prescale;

    float sq = s * s;
#pragma unroll
    for (int off = 16; off >= 1; off >>= 1) sq += __shfl_xor(sq, off, 64);
    const float scale = sq / ((1.0f + sq) * sqrtf(sq + 1e-7f));
    const float o = scale * s;
    if (FINAL) {
        out[((size_t)b * N_ + n) * D_ + d] = o;       // [B][N][D]
    } else {
        const float o_next = __shfl_down(o, 1, 64);
        if ((d & 1) == 0) {
            const unsigned int val = pk_bf16(o, o_next);
            const int l = (d >> 3) * 16 + (b & 15);
            ofrag_u32[(((n * 4 + (b >> 4)) * 64) + l) * 4 + ((d & 7) >> 1)] = val;
        }
    }
}

// ---------------- fused b-update + softmax: LDS-staged W, in-LDS transpose ------
// Block = 2 i. Stage wbf rows (i_e,i_o) for ALL 32 n = 64 KB LDS, coalesced
// (rows i_e,i_o are adjacent => 2 KB contiguous per n). One barrier. Then the
// r12 flow with A-frags assembled from LDS via the r16-verified u32 shift/or.
template<int FIRST>
__global__ __launch_bounds__(512, 2) void k_updsm(const unsigned int* __restrict__ wbfu,
                                                  const float* __restrict__ inT,
                                                  const uint4* __restrict__ ofrag,
                                                  float* __restrict__ bT,
                                                  float* __restrict__ cT) {
    __shared__ __align__(16) unsigned int lds[16384];   // 64 KB = [n][2 i][256 u32]
    const int t = threadIdx.x, w = t >> 6, l = t & 63;
    const int btile = w & 3;
    const int il = w >> 2;
    const int i = blockIdx.x * 2 + il;
    const int g = l >> 4, kl = l & 15;
    const int bp = btile * 16 + kl;           // b'
    const int kh = kl >> 1;
    const bool odd = (kl & 1) != 0;

    // ---- stage: chunk n = 512 u32 (= rows i_e,i_o) at wbfu + (n*I + 2*blk)*256
    {
        const unsigned int* src = wbfu + (size_t)(blockIdx.x * 2) * 256;
#pragma unroll
        for (int q = 0; q < 4; ++q) {
            const int n = w + 8 * q;
            const uint4* s4 = (const uint4*)(src + (size_t)n * (I_ * 256));
            uint4* d4 = (uint4*)(lds + n * 512);
            __builtin_amdgcn_global_load_lds(
                (const AS1 void*)(const void*)(s4 + l),
                (AS3 void*)(void*)(d4), 16, 0, 0);
            __builtin_amdgcn_global_load_lds(
                (const AS1 void*)(const void*)(s4 + 64 + l),
                (AS3 void*)(void*)(d4 + 64), 16, 0, 0);
        }
    }

    float x4[4];
    {
        const float* xp = inT + (size_t)i * (K_ * B_) + bp;
#pragma unroll
        for (int r = 0; r < 4; ++r) x4[r] = xp[(4 * g + r) * B_];
    }
    __syncthreads();                       // drains vmcnt -> tiles resident

    float bn[N_];
#pragma unroll
    for (int n = 0; n < N_; ++n) {
        union { uint4 q; short8_t v; } of, af;
        of.q = ofrag[(n * 4 + btile) * 64 + l];
        // A-frag from LDS (r16-verified formula): row base (n*2+il)*256
        const unsigned int* wr = lds + (n * 2 + il) * 256 + 64 * g + kh;
        union { unsigned int u[4]; uint4 q; } au;
#pragma unroll
        for (int p = 0; p < 4; ++p) {
            const unsigned int A  = wr[16 * p];       // d = 8g+2p
            const unsigned int Bv = wr[16 * p + 8];   // d = 8g+2p+1
            au.u[p] = odd ? ((A >> 16) | (Bv & 0xffff0000u))
                          : ((A & 0xffffu) | (Bv << 16));
        }
        af.q = au.q;
        f32x4_t acc = {0.f, 0.f, 0.f, 0.f};
        acc = __builtin_amdgcn_mfma_f32_16x16x32_bf16(af.v, of.v, acc, 0, 0, 0);
        float gp = 0.f;
#pragma unroll
        for (int r = 0; r < 4; ++r) gp = fmaf(acc[r], x4[r], gp);
        gp += __shfl_xor(gp, 16, 64);
        gp += __shfl_xor(gp, 32, 64);
        const size_t bi = ((size_t)n * I_ + i) * B_ + bp;
        if (FIRST) {
            if (l < 16) bT[bi] = gp;
        } else {
            gp += bT[bi];
        }
        bn[n] = gp;
    }

    float mx = bn[0];
#pragma unroll
    for (int n = 1; n < N_; ++n) mx = fmaxf(mx, bn[n]);
    float sum = 0.f;
#pragma unroll
    for (int n = 0; n < N_; ++n) { bn[n] = __expf(bn[n] - mx); sum += bn[n]; }
    const float inv = 1.0f / sum;
    if (l < 16) {
#pragma unroll
        for (int n = 0; n < N_; ++n)
            cT[((size_t)n * I_ + i) * B_ + bp] = bn[n] * inv;
    }
}

extern "C" void kernel_launch(void* const* d_in, const int* in_sizes, int n_in,
                              void* d_out, int out_size, void* d_ws, size_t ws_size,
                              hipStream_t stream) {
    const float* inputs = (const float*)d_in[0];
    const float* W      = (const float*)d_in[1];
    float* out = (float*)d_out;
    float* ws  = (float*)d_ws;
    float* inT   = ws + OFF_INT;
    float* cT    = ws + OFF_CT;
    float* bT    = ws + OFF_BT;
    float* spart = ws + OFF_SPART;
    unsigned int* ofrag_u32 = (unsigned int*)(ws + OFF_OFRAG);
    uint4* ofrag = (uint4*)(ws + OFF_OFRAG);
    uint4* xfrag = (uint4*)(ws + OFF_XFRAG);
    uint4* wbf4  = (uint4*)(ws + OFF_WBF);
    const unsigned int* wbfu = (const unsigned int*)(ws + OFF_WBF);

    k_wconv<<<(N_ * I_ * D_ * K_) / (8 * 256), 256, 0, stream>>>(W, wbf4);
    k_prep<<<I_, 256, 0, stream>>>(inputs, inT, xfrag);
    // r = 0 (uniform c = 1/N as prescale)
    k_sweep_mfma<1><<<dim3(SCH_, N_), 512, 0, stream>>>(wbf4, xfrag, cT, spart);
    k_reduce<0><<<256, 256, 0, stream>>>(spart, ofrag_u32, out, 1.0f / N_);
    k_updsm<1><<<I_ / 2, 512, 0, stream>>>(wbfu, inT, ofrag, bT, cT);
    // r = 1
    k_sweep_mfma<0><<<dim3(SCH_, N_), 512, 0, stream>>>(wbf4, xfrag, cT, spart);
    k_reduce<0><<<256, 256, 0, stream>>>(spart, ofrag_u32, out, 1.0f);
    k_updsm<0><<<I_ / 2, 512, 0, stream>>>(wbfu, inT, ofrag, bT, cT);
    // r = 2
    k_sweep_mfma<0><<<dim3(SCH_, N_), 512, 0, stream>>>(wbf4, xfrag, cT, spart);
    k_reduce<1><<<256, 256, 0, stream>>>(spart, ofrag_u32, out, 1.0f);
}